// Round 1
// baseline (361.626 us; speedup 1.0000x reference)
//
#include <hip/hip_runtime.h>
#include <hip/hip_bf16.h>

// Problem dims
#define T_TOK 4096
#define H_DIM 1024
#define I_DIM 1408
#define E_NUM 8
#define P_CAP 8192   // exactly 2*T pairs

typedef __bf16 bf16;
typedef __bf16 bf16x4 __attribute__((ext_vector_type(4)));
typedef __bf16 bf16x8 __attribute__((ext_vector_type(8)));
typedef float  f32x4  __attribute__((ext_vector_type(4)));

// async global->LDS, 16B per lane; LDS dest must be wave-uniform base (+lane*16 implicit)
__device__ __forceinline__ void load_lds16(const void* g, void* l) {
  __builtin_amdgcn_global_load_lds((const __attribute__((address_space(1))) void*)g,
                                   (__attribute__((address_space(3))) void*)l, 16, 0, 0);
}

// ---------------- fp32 -> bf16 cast ----------------
__global__ __launch_bounds__(256) void cast_f2b(const float* __restrict__ s,
                                                bf16* __restrict__ d, int n) {
  int i = (blockIdx.x * 256 + threadIdx.x) * 4;
  if (i >= n) return;
  float4 v = *(const float4*)(s + i);
  bf16x4 o;
  o.x = (bf16)v.x; o.y = (bf16)v.y; o.z = (bf16)v.z; o.w = (bf16)v.w;
  *(bf16x4*)(d + i) = o;
}

// ---------------- router: fp32 logits, top-2, renormalized weights ----------------
__global__ __launch_bounds__(256) void router_kernel(const float* __restrict__ x,
                                                     const float* __restrict__ rw,
                                                     int* __restrict__ tidx,
                                                     float* __restrict__ tw) {
  int t = blockIdx.x * 4 + (threadIdx.x >> 6);
  int lane = threadIdx.x & 63;
  const float* xr = x + (size_t)t * H_DIM;
  float acc[E_NUM];
#pragma unroll
  for (int e = 0; e < E_NUM; ++e) acc[e] = 0.f;
  for (int c = lane; c < H_DIM; c += 64) {
    float xv = xr[c];
#pragma unroll
    for (int e = 0; e < E_NUM; ++e) acc[e] += xv * rw[e * H_DIM + c];
  }
#pragma unroll
  for (int e = 0; e < E_NUM; ++e)
    for (int s = 32; s > 0; s >>= 1) acc[e] += __shfl_down(acc[e], s, 64);
  if (lane == 0) {
    int a = 0;
#pragma unroll
    for (int e = 1; e < E_NUM; ++e) if (acc[e] > acc[a]) a = e;
    int b = (a == 0) ? 1 : 0;
#pragma unroll
    for (int e = 0; e < E_NUM; ++e) if (e != a && acc[e] > acc[b]) b = e;
    // softmax denominator cancels in top-k renorm: w = exp(l-la)/(1+exp(lb-la))
    float pb = expf(acc[b] - acc[a]);
    float inv = 1.f / (1.f + pb);
    tidx[t * 2] = a; tidx[t * 2 + 1] = b;
    tw[t * 2] = inv; tw[t * 2 + 1] = pb * inv;
  }
}

// ---------------- bucketize: counts, offsets, scatter pair lists ----------------
__global__ __launch_bounds__(256) void bucket_kernel(const int* __restrict__ tidx,
                                                     const float* __restrict__ tw,
                                                     int* __restrict__ pair_tok,
                                                     float* __restrict__ pair_w,
                                                     int* __restrict__ counts,
                                                     int* __restrict__ offsets) {
  __shared__ int sc[E_NUM], so[E_NUM], scur[E_NUM];
  int tid = threadIdx.x;
  if (tid < E_NUM) sc[tid] = 0;
  __syncthreads();
  for (int p = tid; p < T_TOK * 2; p += 256) atomicAdd(&sc[tidx[p]], 1);
  __syncthreads();
  if (tid == 0) {
    int run = 0;
    for (int e = 0; e < E_NUM; ++e) { so[e] = run; run += sc[e]; }
  }
  __syncthreads();
  if (tid < E_NUM) scur[tid] = so[tid];
  __syncthreads();
  for (int t = tid; t < T_TOK; t += 256) {
#pragma unroll
    for (int k = 0; k < 2; ++k) {
      int e = tidx[t * 2 + k];
      int pos = atomicAdd(&scur[e], 1);
      pair_tok[pos] = t;
      pair_w[pos] = tw[t * 2 + k];
    }
  }
  if (tid < E_NUM) { counts[tid] = sc[tid]; offsets[tid] = so[tid]; }
}

// ---------------- GEMM1: mid = silu(x@Wg^T) * (x@Wu^T), gathered rows ----------------
// 128x128 tile, BK=64, 4 waves (2x2), 16x16x32 bf16 MFMA, two accumulator sets.
__global__ __launch_bounds__(256, 2)
void gemm1_kernel(const bf16* __restrict__ xb, const bf16* __restrict__ wgb,
                  const bf16* __restrict__ wub, const int* __restrict__ pair_tok,
                  const int* __restrict__ counts, const int* __restrict__ offsets,
                  bf16* __restrict__ mid) {
  const int e = blockIdx.z;
  const int cnt = counts[e];
  const int m0 = blockIdx.y << 7;
  if (m0 >= cnt) return;
  const int off = offsets[e];
  const int n0 = blockIdx.x << 7;

  __shared__ bf16 As[128 * 64];
  __shared__ bf16 Bgs[128 * 64];
  __shared__ bf16 Bus[128 * 64];

  const int tid = threadIdx.x;
  const int wave = tid >> 6;
  const int lane = tid & 63;
  const int wm = (wave >> 1) << 6;
  const int wn = (wave & 1) << 6;

  const bf16* wg_e = wgb + (size_t)e * (I_DIM * H_DIM);
  const bf16* wu_e = wub + (size_t)e * (I_DIM * H_DIM);

  int arow[4], acs[4], atok[4];
#pragma unroll
  for (int j = 0; j < 4; ++j) {
    int seg = ((wave << 2) + j) * 64 + lane;
    arow[j] = seg >> 3;            // 0..127 within tile
    acs[j]  = (seg & 7) << 3;      // col start (8 bf16 per 16B)
    int gr = m0 + arow[j];
    int cr = gr < cnt ? gr : cnt - 1;  // clamp gather for tail rows
    atok[j] = pair_tok[off + cr];
  }

  f32x4 accg[4][4], accu[4][4];
#pragma unroll
  for (int i = 0; i < 4; ++i)
#pragma unroll
    for (int j = 0; j < 4; ++j) {
      accg[i][j] = (f32x4){0.f, 0.f, 0.f, 0.f};
      accu[i][j] = (f32x4){0.f, 0.f, 0.f, 0.f};
    }

  for (int k0 = 0; k0 < H_DIM; k0 += 64) {
#pragma unroll
    for (int j = 0; j < 4; ++j) {
      int base = ((wave << 2) + j) << 9;  // *512 elems = 1KB per wave-instr
      load_lds16(xb + (size_t)atok[j] * H_DIM + k0 + acs[j], As + base);
      load_lds16(wg_e + (size_t)(n0 + arow[j]) * H_DIM + k0 + acs[j], Bgs + base);
      load_lds16(wu_e + (size_t)(n0 + arow[j]) * H_DIM + k0 + acs[j], Bus + base);
    }
    __syncthreads();
#pragma unroll
    for (int ks = 0; ks < 2; ++ks) {
      const int kc = (ks << 5) + ((lane >> 4) << 3);
      const int lr = lane & 15;
      bf16x8 a[4], bg[4], bu[4];
#pragma unroll
      for (int i = 0; i < 4; ++i)
        a[i] = *(const bf16x8*)(As + (wm + (i << 4) + lr) * 64 + kc);
#pragma unroll
      for (int j = 0; j < 4; ++j) {
        bg[j] = *(const bf16x8*)(Bgs + (wn + (j << 4) + lr) * 64 + kc);
        bu[j] = *(const bf16x8*)(Bus + (wn + (j << 4) + lr) * 64 + kc);
      }
#pragma unroll
      for (int i = 0; i < 4; ++i)
#pragma unroll
        for (int j = 0; j < 4; ++j) {
          accg[i][j] = __builtin_amdgcn_mfma_f32_16x16x32_bf16(a[i], bg[j], accg[i][j], 0, 0, 0);
          accu[i][j] = __builtin_amdgcn_mfma_f32_16x16x32_bf16(a[i], bu[j], accu[i][j], 0, 0, 0);
        }
    }
    __syncthreads();
  }

  const int lr = lane & 15, qd = lane >> 4;
#pragma unroll
  for (int i = 0; i < 4; ++i) {
#pragma unroll
    for (int r = 0; r < 4; ++r) {
      int row = wm + (i << 4) + (qd << 2) + r;  // C/D: row = quad*4+reg
      int gr = m0 + row;
      if (gr < cnt) {
        bf16* mrow = mid + (size_t)(off + gr) * I_DIM + n0 + wn;
#pragma unroll
        for (int j = 0; j < 4; ++j) {
          float g = accg[i][j][r], u = accu[i][j][r];
          float s = g / (1.f + __expf(-g));
          mrow[(j << 4) + lr] = (bf16)(s * u);  // C/D: col = lane&15
        }
      }
    }
  }
}

// ---------------- GEMM2: out[t] += w * (mid @ Wd^T) ----------------
__global__ __launch_bounds__(256, 2)
void gemm2_kernel(const bf16* __restrict__ mid, const bf16* __restrict__ wdb,
                  const int* __restrict__ pair_tok, const float* __restrict__ pair_w,
                  const int* __restrict__ counts, const int* __restrict__ offsets,
                  float* __restrict__ out) {
  const int e = blockIdx.z;
  const int cnt = counts[e];
  const int m0 = blockIdx.y << 7;
  if (m0 >= cnt) return;
  const int off = offsets[e];
  const int n0 = blockIdx.x << 7;

  __shared__ bf16 As[128 * 64];
  __shared__ bf16 Bs[128 * 64];

  const int tid = threadIdx.x;
  const int wave = tid >> 6;
  const int lane = tid & 63;
  const int wm = (wave >> 1) << 6;
  const int wn = (wave & 1) << 6;

  const bf16* wd_e = wdb + (size_t)e * (H_DIM * I_DIM);

  int arow[4], acs[4];
  size_t apos[4];
#pragma unroll
  for (int j = 0; j < 4; ++j) {
    int seg = ((wave << 2) + j) * 64 + lane;
    arow[j] = seg >> 3;
    acs[j]  = (seg & 7) << 3;
    int gr = m0 + arow[j];
    int cr = gr < cnt ? gr : cnt - 1;
    apos[j] = (size_t)(off + cr) * I_DIM + acs[j];
  }

  f32x4 acc[4][4];
#pragma unroll
  for (int i = 0; i < 4; ++i)
#pragma unroll
    for (int j = 0; j < 4; ++j) acc[i][j] = (f32x4){0.f, 0.f, 0.f, 0.f};

  for (int k0 = 0; k0 < I_DIM; k0 += 64) {  // 22 iters
#pragma unroll
    for (int j = 0; j < 4; ++j) {
      int base = ((wave << 2) + j) << 9;
      load_lds16(mid + apos[j] + k0, As + base);
      load_lds16(wd_e + (size_t)(n0 + arow[j]) * I_DIM + k0 + acs[j], Bs + base);
    }
    __syncthreads();
#pragma unroll
    for (int ks = 0; ks < 2; ++ks) {
      const int kc = (ks << 5) + ((lane >> 4) << 3);
      const int lr = lane & 15;
      bf16x8 a[4], b[4];
#pragma unroll
      for (int i = 0; i < 4; ++i)
        a[i] = *(const bf16x8*)(As + (wm + (i << 4) + lr) * 64 + kc);
#pragma unroll
      for (int j = 0; j < 4; ++j)
        b[j] = *(const bf16x8*)(Bs + (wn + (j << 4) + lr) * 64 + kc);
#pragma unroll
      for (int i = 0; i < 4; ++i)
#pragma unroll
        for (int j = 0; j < 4; ++j)
          acc[i][j] = __builtin_amdgcn_mfma_f32_16x16x32_bf16(a[i], b[j], acc[i][j], 0, 0, 0);
    }
    __syncthreads();
  }

  const int lr = lane & 15, qd = lane >> 4;
#pragma unroll
  for (int i = 0; i < 4; ++i) {
#pragma unroll
    for (int r = 0; r < 4; ++r) {
      int row = wm + (i << 4) + (qd << 2) + r;
      int gr = m0 + row;
      if (gr < cnt) {
        int t = pair_tok[off + gr];
        float w = pair_w[off + gr];
        float* orow = out + (size_t)t * H_DIM + n0 + wn;
#pragma unroll
        for (int j = 0; j < 4; ++j)
          atomicAdd(orow + (j << 4) + lr, w * acc[i][j][r]);
      }
    }
  }
}

extern "C" void kernel_launch(void* const* d_in, const int* in_sizes, int n_in,
                              void* d_out, int out_size, void* d_ws, size_t ws_size,
                              hipStream_t stream) {
  const float* x  = (const float*)d_in[0];   // [2,2048,1024]
  const float* rw = (const float*)d_in[1];   // [8,1024]
  const float* wg = (const float*)d_in[2];   // [8,1408,1024]
  const float* wu = (const float*)d_in[3];   // [8,1408,1024]
  const float* wd = (const float*)d_in[4];   // [8,1024,1408]
  float* out = (float*)d_out;

  char* ws = (char*)d_ws;
  bf16*  xb      = (bf16*)(ws);                    // 8,388,608 B
  bf16*  wgb     = (bf16*)(ws + 8388608);          // 23,068,672 B
  bf16*  wub     = (bf16*)(ws + 31457280);         // 23,068,672 B
  bf16*  wdb     = (bf16*)(ws + 54525952);         // 23,068,672 B
  bf16*  mid     = (bf16*)(ws + 77594624);         // 23,068,672 B
  int*   tidx    = (int*)(ws + 100663296);         // 32,768 B
  float* tw      = (float*)(ws + 100696064);       // 32,768 B
  int*   ptok    = (int*)(ws + 100728832);         // 32,768 B
  float* pw      = (float*)(ws + 100761600);       // 32,768 B
  int*   counts  = (int*)(ws + 100794368);         // 32 B
  int*   offsets = (int*)(ws + 100794400);         // 32 B

  hipMemsetAsync(d_out, 0, (size_t)T_TOK * H_DIM * sizeof(float), stream);
  cast_f2b<<<4096, 256, 0, stream>>>(x, xb, T_TOK * H_DIM);
  cast_f2b<<<11264, 256, 0, stream>>>(wg, wgb, E_NUM * I_DIM * H_DIM);
  cast_f2b<<<11264, 256, 0, stream>>>(wu, wub, E_NUM * I_DIM * H_DIM);
  cast_f2b<<<11264, 256, 0, stream>>>(wd, wdb, E_NUM * H_DIM * I_DIM);
  router_kernel<<<1024, 256, 0, stream>>>(x, rw, tidx, tw);
  bucket_kernel<<<1, 256, 0, stream>>>(tidx, tw, ptok, pw, counts, offsets);
  gemm1_kernel<<<dim3(11, 32, 8), 256, 0, stream>>>(xb, wgb, wub, ptok, counts, offsets, mid);
  gemm2_kernel<<<dim3(8, 32, 8), 256, 0, stream>>>(mid, wdb, ptok, pw, counts, offsets, out);
}

// Round 2
// 345.786 us; speedup vs baseline: 1.0458x; 1.0458x over previous
//
#include <hip/hip_runtime.h>
#include <hip/hip_bf16.h>

// Problem dims
#define T_TOK 4096
#define H_DIM 1024
#define I_DIM 1408
#define E_NUM 8
#define P_CAP 8192   // exactly 2*T pairs
#define GRID_Y 71    // max sum(ceil(cnt_e/128)) = 8192/128 + 7

typedef __bf16 bf16;
typedef __bf16 bf16x4 __attribute__((ext_vector_type(4)));
typedef __bf16 bf16x8 __attribute__((ext_vector_type(8)));
typedef float  f32x4  __attribute__((ext_vector_type(4)));

// async global->LDS, 16B per lane; LDS dest must be wave-uniform base (+lane*16 implicit)
// global source address is per-lane free -> we use it to bank-swizzle the LDS layout.
__device__ __forceinline__ void load_lds16(const void* g, void* l) {
  __builtin_amdgcn_global_load_lds((const __attribute__((address_space(1))) void*)g,
                                   (__attribute__((address_space(3))) void*)l, 16, 0, 0);
}

// ---------------- fused fp32 -> bf16 casts (x, wg, wu, wd) ----------------
__global__ __launch_bounds__(256) void cast_all(const float* __restrict__ x,
                                                const float* __restrict__ wg,
                                                const float* __restrict__ wu,
                                                const float* __restrict__ wd,
                                                bf16* __restrict__ xb, bf16* __restrict__ wgb,
                                                bf16* __restrict__ wub, bf16* __restrict__ wdb) {
  int b = blockIdx.x;
  const float* s; bf16* d; int base;
  if (b < 4096)       { s = x;  d = xb;  base = b; }
  else if (b < 15360) { s = wg; d = wgb; base = b - 4096; }
  else if (b < 26624) { s = wu; d = wub; base = b - 15360; }
  else                { s = wd; d = wdb; base = b - 26624; }
  size_t i = ((size_t)base * 256 + threadIdx.x) * 4;
  float4 v = *(const float4*)(s + i);
  bf16x4 o;
  o.x = (bf16)v.x; o.y = (bf16)v.y; o.z = (bf16)v.z; o.w = (bf16)v.w;
  *(bf16x4*)(d + i) = o;
}

// ---------------- router: fp32 logits, top-2, renormalized weights ----------------
__global__ __launch_bounds__(256) void router_kernel(const float* __restrict__ x,
                                                     const float* __restrict__ rw,
                                                     int* __restrict__ tidx,
                                                     float* __restrict__ tw) {
  int t = blockIdx.x * 4 + (threadIdx.x >> 6);
  int lane = threadIdx.x & 63;
  const float* xr = x + (size_t)t * H_DIM;
  float acc[E_NUM];
#pragma unroll
  for (int e = 0; e < E_NUM; ++e) acc[e] = 0.f;
  for (int c = lane; c < H_DIM; c += 64) {
    float xv = xr[c];
#pragma unroll
    for (int e = 0; e < E_NUM; ++e) acc[e] += xv * rw[e * H_DIM + c];
  }
#pragma unroll
  for (int e = 0; e < E_NUM; ++e)
    for (int s = 32; s > 0; s >>= 1) acc[e] += __shfl_down(acc[e], s, 64);
  if (lane == 0) {
    int a = 0;
#pragma unroll
    for (int e = 1; e < E_NUM; ++e) if (acc[e] > acc[a]) a = e;
    int b = (a == 0) ? 1 : 0;
#pragma unroll
    for (int e = 0; e < E_NUM; ++e) if (e != a && acc[e] > acc[b]) b = e;
    // softmax denominator cancels in top-k renorm: w = 1/(1+exp(lb-la))
    float pb = expf(acc[b] - acc[a]);
    float inv = 1.f / (1.f + pb);
    tidx[t * 2] = a; tidx[t * 2 + 1] = b;
    tw[t * 2] = inv; tw[t * 2 + 1] = pb * inv;
  }
}

// ---------------- bucketize: counts, offsets, pair lists, block table ----------------
__global__ __launch_bounds__(256) void bucket_kernel(const int* __restrict__ tidx,
                                                     const float* __restrict__ tw,
                                                     int* __restrict__ pair_tok,
                                                     float* __restrict__ pair_w,
                                                     int* __restrict__ counts,
                                                     int* __restrict__ offsets,
                                                     int* __restrict__ blk2e,
                                                     int* __restrict__ blk2m) {
  __shared__ int sc[E_NUM], so[E_NUM], scur[E_NUM];
  int tid = threadIdx.x;
  if (tid < E_NUM) sc[tid] = 0;
  __syncthreads();
  for (int p = tid; p < T_TOK * 2; p += 256) atomicAdd(&sc[tidx[p]], 1);
  __syncthreads();
  if (tid == 0) {
    int run = 0, nb = 0;
    for (int e = 0; e < E_NUM; ++e) {
      so[e] = run; run += sc[e];
      for (int m = 0; m * 128 < sc[e]; ++m) { blk2e[nb] = e; blk2m[nb] = m; ++nb; }
    }
    for (; nb < GRID_Y; ++nb) { blk2e[nb] = -1; blk2m[nb] = 0; }
  }
  __syncthreads();
  if (tid < E_NUM) scur[tid] = so[tid];
  __syncthreads();
  for (int t = tid; t < T_TOK; t += 256) {
#pragma unroll
    for (int k = 0; k < 2; ++k) {
      int e = tidx[t * 2 + k];
      int pos = atomicAdd(&scur[e], 1);
      pair_tok[pos] = t;
      pair_w[pos] = tw[t * 2 + k];
    }
  }
  if (tid < E_NUM) { counts[tid] = sc[tid]; offsets[tid] = so[tid]; }
}

// ---------------- GEMM1: mid = silu(x@Wg^T) * (x@Wu^T), gathered rows ----------------
// 128x128 tile, BK=64, 4 waves (2x2), 16x16x32 bf16 MFMA, two accumulator sets.
// LDS bank-conflict fix: XOR-swizzle the stored chunk via the global source
// address (c_stored = c ^ (row&7)); un-swizzle on the fragment read.
__global__ __launch_bounds__(256, 2)
void gemm1_kernel(const bf16* __restrict__ xb, const bf16* __restrict__ wgb,
                  const bf16* __restrict__ wub, const int* __restrict__ pair_tok,
                  const int* __restrict__ counts, const int* __restrict__ offsets,
                  const int* __restrict__ blk2e, const int* __restrict__ blk2m,
                  bf16* __restrict__ mid) {
  const int e = blk2e[blockIdx.y];
  if (e < 0) return;
  const int cnt = counts[e];
  const int m0 = blk2m[blockIdx.y] << 7;
  const int off = offsets[e];
  const int n0 = blockIdx.x << 7;

  __shared__ bf16 As[128 * 64];
  __shared__ bf16 Bgs[128 * 64];
  __shared__ bf16 Bus[128 * 64];

  const int tid = threadIdx.x;
  const int wave = tid >> 6;
  const int lane = tid & 63;
  const int wm = (wave >> 1) << 6;
  const int wn = (wave & 1) << 6;

  const bf16* wg_e = wgb + (size_t)e * (I_DIM * H_DIM);
  const bf16* wu_e = wub + (size_t)e * (I_DIM * H_DIM);

  int arow[4], acs[4], atok[4];
#pragma unroll
  for (int j = 0; j < 4; ++j) {
    int seg = ((wave << 2) + j) * 64 + lane;
    int row = seg >> 3;
    arow[j] = row;                               // 0..127 within tile
    acs[j]  = ((seg & 7) ^ (row & 7)) << 3;      // swizzled col start (8 bf16 / 16B)
    int gr = m0 + row;
    int cr = gr < cnt ? gr : cnt - 1;            // clamp gather for tail rows
    atok[j] = pair_tok[off + cr];
  }

  f32x4 accg[4][4], accu[4][4];
#pragma unroll
  for (int i = 0; i < 4; ++i)
#pragma unroll
    for (int j = 0; j < 4; ++j) {
      accg[i][j] = (f32x4){0.f, 0.f, 0.f, 0.f};
      accu[i][j] = (f32x4){0.f, 0.f, 0.f, 0.f};
    }

  const int lr = lane & 15;
  const int sw = lr & 7;   // read-side un-swizzle (row&7 == lr&7 for all frag rows)
  const int qd = lane >> 4;

  for (int k0 = 0; k0 < H_DIM; k0 += 64) {
#pragma unroll
    for (int j = 0; j < 4; ++j) {
      int base = ((wave << 2) + j) << 9;  // *512 elems = 1KB per wave-instr
      load_lds16(xb + (size_t)atok[j] * H_DIM + k0 + acs[j], As + base);
      load_lds16(wg_e + (size_t)(n0 + arow[j]) * H_DIM + k0 + acs[j], Bgs + base);
      load_lds16(wu_e + (size_t)(n0 + arow[j]) * H_DIM + k0 + acs[j], Bus + base);
    }
    __syncthreads();
#pragma unroll
    for (int ks = 0; ks < 2; ++ks) {
      const int kc = (((ks << 2) + qd) ^ sw) << 3;   // un-swizzled chunk -> elem offset
      bf16x8 a[4], bg[4], bu[4];
#pragma unroll
      for (int i = 0; i < 4; ++i)
        a[i] = *(const bf16x8*)(As + (wm + (i << 4) + lr) * 64 + kc);
#pragma unroll
      for (int j = 0; j < 4; ++j) {
        bg[j] = *(const bf16x8*)(Bgs + (wn + (j << 4) + lr) * 64 + kc);
        bu[j] = *(const bf16x8*)(Bus + (wn + (j << 4) + lr) * 64 + kc);
      }
#pragma unroll
      for (int i = 0; i < 4; ++i)
#pragma unroll
        for (int j = 0; j < 4; ++j) {
          accg[i][j] = __builtin_amdgcn_mfma_f32_16x16x32_bf16(a[i], bg[j], accg[i][j], 0, 0, 0);
          accu[i][j] = __builtin_amdgcn_mfma_f32_16x16x32_bf16(a[i], bu[j], accu[i][j], 0, 0, 0);
        }
    }
    __syncthreads();
  }

#pragma unroll
  for (int i = 0; i < 4; ++i) {
#pragma unroll
    for (int r = 0; r < 4; ++r) {
      int row = wm + (i << 4) + (qd << 2) + r;  // C/D: row = quad*4+reg
      int gr = m0 + row;
      if (gr < cnt) {
        bf16* mrow = mid + (size_t)(off + gr) * I_DIM + n0 + wn;
#pragma unroll
        for (int j = 0; j < 4; ++j) {
          float g = accg[i][j][r], u = accu[i][j][r];
          float s = g / (1.f + __expf(-g));
          mrow[(j << 4) + lr] = (bf16)(s * u);  // C/D: col = lane&15
        }
      }
    }
  }
}

// ---------------- GEMM2: out[t] += w * (mid @ Wd^T) ----------------
__global__ __launch_bounds__(256, 2)
void gemm2_kernel(const bf16* __restrict__ mid, const bf16* __restrict__ wdb,
                  const int* __restrict__ pair_tok, const float* __restrict__ pair_w,
                  const int* __restrict__ counts, const int* __restrict__ offsets,
                  const int* __restrict__ blk2e, const int* __restrict__ blk2m,
                  float* __restrict__ out) {
  const int e = blk2e[blockIdx.y];
  if (e < 0) return;
  const int cnt = counts[e];
  const int m0 = blk2m[blockIdx.y] << 7;
  const int off = offsets[e];
  const int n0 = blockIdx.x << 7;

  __shared__ bf16 As[128 * 64];
  __shared__ bf16 Bs[128 * 64];

  const int tid = threadIdx.x;
  const int wave = tid >> 6;
  const int lane = tid & 63;
  const int wm = (wave >> 1) << 6;
  const int wn = (wave & 1) << 6;

  const bf16* wd_e = wdb + (size_t)e * (H_DIM * I_DIM);

  int arow[4], acs[4];
  size_t apos[4];
#pragma unroll
  for (int j = 0; j < 4; ++j) {
    int seg = ((wave << 2) + j) * 64 + lane;
    int row = seg >> 3;
    arow[j] = row;
    acs[j]  = ((seg & 7) ^ (row & 7)) << 3;      // swizzled col start
    int gr = m0 + row;
    int cr = gr < cnt ? gr : cnt - 1;
    apos[j] = (size_t)(off + cr) * I_DIM + acs[j];
  }

  f32x4 acc[4][4];
#pragma unroll
  for (int i = 0; i < 4; ++i)
#pragma unroll
    for (int j = 0; j < 4; ++j) acc[i][j] = (f32x4){0.f, 0.f, 0.f, 0.f};

  const int lr = lane & 15;
  const int sw = lr & 7;
  const int qd = lane >> 4;

  for (int k0 = 0; k0 < I_DIM; k0 += 64) {  // 22 iters
#pragma unroll
    for (int j = 0; j < 4; ++j) {
      int base = ((wave << 2) + j) << 9;
      load_lds16(mid + apos[j] + k0, As + base);
      load_lds16(wd_e + (size_t)(n0 + arow[j]) * I_DIM + k0 + acs[j], Bs + base);
    }
    __syncthreads();
#pragma unroll
    for (int ks = 0; ks < 2; ++ks) {
      const int kc = (((ks << 2) + qd) ^ sw) << 3;
      bf16x8 a[4], b[4];
#pragma unroll
      for (int i = 0; i < 4; ++i)
        a[i] = *(const bf16x8*)(As + (wm + (i << 4) + lr) * 64 + kc);
#pragma unroll
      for (int j = 0; j < 4; ++j)
        b[j] = *(const bf16x8*)(Bs + (wn + (j << 4) + lr) * 64 + kc);
#pragma unroll
      for (int i = 0; i < 4; ++i)
#pragma unroll
        for (int j = 0; j < 4; ++j)
          acc[i][j] = __builtin_amdgcn_mfma_f32_16x16x32_bf16(a[i], b[j], acc[i][j], 0, 0, 0);
    }
    __syncthreads();
  }

#pragma unroll
  for (int i = 0; i < 4; ++i) {
#pragma unroll
    for (int r = 0; r < 4; ++r) {
      int row = wm + (i << 4) + (qd << 2) + r;
      int gr = m0 + row;
      if (gr < cnt) {
        int t = pair_tok[off + gr];
        float w = pair_w[off + gr];
        float* orow = out + (size_t)t * H_DIM + n0 + wn;
#pragma unroll
        for (int j = 0; j < 4; ++j)
          atomicAdd(orow + (j << 4) + lr, w * acc[i][j][r]);
      }
    }
  }
}

extern "C" void kernel_launch(void* const* d_in, const int* in_sizes, int n_in,
                              void* d_out, int out_size, void* d_ws, size_t ws_size,
                              hipStream_t stream) {
  const float* x  = (const float*)d_in[0];   // [2,2048,1024]
  const float* rw = (const float*)d_in[1];   // [8,1024]
  const float* wg = (const float*)d_in[2];   // [8,1408,1024]
  const float* wu = (const float*)d_in[3];   // [8,1408,1024]
  const float* wd = (const float*)d_in[4];   // [8,1024,1408]
  float* out = (float*)d_out;

  char* ws = (char*)d_ws;
  bf16*  xb      = (bf16*)(ws);                    // 8,388,608 B
  bf16*  wgb     = (bf16*)(ws + 8388608);          // 23,068,672 B
  bf16*  wub     = (bf16*)(ws + 31457280);         // 23,068,672 B
  bf16*  wdb     = (bf16*)(ws + 54525952);         // 23,068,672 B
  bf16*  mid     = (bf16*)(ws + 77594624);         // 23,068,672 B
  int*   tidx    = (int*)(ws + 100663296);         // 32,768 B
  float* tw      = (float*)(ws + 100696064);       // 32,768 B
  int*   ptok    = (int*)(ws + 100728832);         // 32,768 B
  float* pw      = (float*)(ws + 100761600);       // 32,768 B
  int*   counts  = (int*)(ws + 100794368);         // 32 B
  int*   offsets = (int*)(ws + 100794400);         // 32 B
  int*   blk2e   = (int*)(ws + 100794432);         // 284 B
  int*   blk2m   = (int*)(ws + 100794752);         // 284 B

  hipMemsetAsync(d_out, 0, (size_t)T_TOK * H_DIM * sizeof(float), stream);
  cast_all<<<37888, 256, 0, stream>>>(x, wg, wu, wd, xb, wgb, wub, wdb);
  router_kernel<<<1024, 256, 0, stream>>>(x, rw, tidx, tw);
  bucket_kernel<<<1, 256, 0, stream>>>(tidx, tw, ptok, pw, counts, offsets, blk2e, blk2m);
  gemm1_kernel<<<dim3(11, GRID_Y), 256, 0, stream>>>(xb, wgb, wub, ptok, counts, offsets, blk2e, blk2m, mid);
  gemm2_kernel<<<dim3(8, GRID_Y), 256, 0, stream>>>(mid, wdb, ptok, pw, counts, offsets, blk2e, blk2m, out);
}